// Round 14
// baseline (300.788 us; speedup 1.0000x reference)
//
#include <hip/hip_runtime.h>

#define NV 300
#define NA 12
#define ND 4
#define NM (NV*NA)
#define NS 1024
#define NG 1024
#define NSP 4

// workspace float offsets
#define W_VIEWS 0          // 900
#define W_GROT  900        // 32400
#define W_PKP   33300      // 43200
#define W_BATCH 76500
#define SB      134032     // per-batch stride (floats)

#define PB_GPT  0          // 3072
#define PB_ROT  3072       // 32400
#define PB_TB   35472      // 43200 (transposed: [12][NM])
#define PB_TBS  78672      // 43200 (transposed: [12][NM])
#define PB_TN1  121872     // 3600
#define PB_TN2  125472     // 3600
#define PB_VIND 129072     // 300 ints
#define PB_AIND 129372     // 3600 ints

__constant__ float C_L[4][3]  = {{0.02f,0.f,0.f},{0.02f,0.01f,0.f},{0.02f,-0.01f,0.f},{0.f,0.f,0.f}};
__constant__ float C_LS[4][3] = {{0.02f,0.f,0.f},{0.02f,-0.01f,0.f},{0.02f,0.01f,0.f},{0.f,0.f,0.f}};

__device__ __forceinline__ void kp12(const float R[9], const float (*L)[3], float out[12]) {
#pragma unroll
    for (int k = 0; k < 4; ++k)
#pragma unroll
        for (int i = 0; i < 3; ++i)
            out[k*3+i] = R[i*3+0]*L[k][0] + R[i*3+1]*L[k][1] + R[i*3+2]*L[k][2];
}

// fp64 Fibonacci-sphere view i (identical formula to numpy reference)
__device__ __forceinline__ void view_d(int i, float* vx, float* vy, float* vz) {
    const double PI = 3.14159265358979323846;
    double phi = (sqrt(5.0) - 1.0) * 0.5;
    double z = (2.0*i + 1.0)/(double)NV - 1.0;
    double r2 = 1.0 - z*z; r2 = r2 > 0.0 ? r2 : 0.0;
    double r = sqrt(r2);
    double ang = 2.0*PI*(double)i*phi;
    *vx = (float)(r*cos(ang));
    *vy = (float)(r*sin(ang));
    *vz = (float)z;
}

// K1: blocks 0..14 -> views + GRASP_ROT + pkp; blocks 15.. -> gp_trans
__global__ void k_setup(const float* __restrict__ pose, const float* __restrict__ gp,
                        float* W) {
    int bid = blockIdx.x;
    if (bid < 15) {
        int m = bid*256 + threadIdx.x;
        if (m >= NM) return;
        if (m < NV) {
            float x,y,z; view_d(m, &x,&y,&z);
            W[W_VIEWS + 3*m+0] = x; W[W_VIEWS + 3*m+1] = y; W[W_VIEWS + 3*m+2] = z;
        }
        int vi = m / NA, ai = m % NA;
        float vx,vy,vz; view_d(vi, &vx,&vy,&vz);
        float tx = -vx, ty = -vy, tz = -vz;
        float nrm = sqrtf(tx*tx + ty*ty + tz*tz);
        float ax0 = tx/nrm, ax1 = ty/nrm, ax2 = tz/nrm;
        float ay0 = -ax1, ay1 = ax0, ay2 = 0.f;
        float n2 = sqrtf(ay0*ay0 + ay1*ay1 + ay2*ay2);
        if (n2 > 1e-8f) { float d = fmaxf(n2, 1e-12f); ay0 /= d; ay1 /= d; ay2 /= d; }
        else { ay0 = 0.f; ay1 = 1.f; ay2 = 0.f; }
        float az0 = ax1*ay2 - ax2*ay1;
        float az1 = ax2*ay0 - ax0*ay2;
        float az2 = ax0*ay1 - ax1*ay0;
        float angle = (float)(3.14159265358979323846/12.0*(double)ai);
        float c = cosf(angle), s = sinf(angle);
        float G[9];
        G[0]=ax0; G[1]=ay0*c+az0*s; G[2]=-ay0*s+az0*c;
        G[3]=ax1; G[4]=ay1*c+az1*s; G[5]=-ay1*s+az1*c;
        G[6]=ax2; G[7]=ay2*c+az2*s; G[8]=-ay2*s+az2*c;
#pragma unroll
        for (int q=0;q<9;++q) W[W_GROT + 9*m + q] = G[q];
        float pk[12]; kp12(G, C_L, pk);
#pragma unroll
        for (int q=0;q<12;++q) W[W_PKP + 12*m + q] = pk[q];
    } else {
        int idx = (bid-15)*256 + threadIdx.x;   // over B*NG
        int b = idx >> 10, g = idx & (NG-1);
        const float* P = pose + 12*b;
        float x = gp[(size_t)idx*3+0], y = gp[(size_t)idx*3+1], z = gp[(size_t)idx*3+2];
        float* o = W + W_BATCH + (size_t)b*SB + PB_GPT + 3*g;
        o[0] = P[0]*x + P[1]*y + P[2]*z  + P[3];
        o[1] = P[4]*x + P[5]*y + P[6]*z  + P[7];
        o[2] = P[8]*x + P[9]*y + P[10]*z + P[11];
    }
}

// K2: fused vind + align. one 64-thread block per (v, b)
__global__ void k_va(const float* __restrict__ pose, float* W) {
    int v = blockIdx.x, b = blockIdx.y;
    float* WB = W + W_BATCH + (size_t)b*SB;
    int* IB = (int*)W + W_BATCH + (size_t)b*SB;
    const float* P = pose + 12*b;
    int lane = threadIdx.x;  // 0..63, one wave

    __shared__ float vtx[NV], vty[NV], vtz[NV], vn[NV];
    __shared__ float rtr[NA][9];
    __shared__ float tk[NA][12], tks[NA][12];
    __shared__ int s_vi;

    for (int i = lane; i < NV; i += 64) {
        float x = W[W_VIEWS+3*i], y = W[W_VIEWS+3*i+1], z = W[W_VIEWS+3*i+2];
        float a = P[0]*x+P[1]*y+P[2]*z;
        float c = P[4]*x+P[5]*y+P[6]*z;
        float d = P[8]*x+P[9]*y+P[10]*z;
        vtx[i]=a; vty[i]=c; vtz[i]=d;
        vn[i] = a*a + c*c + d*d;
    }
    __syncthreads();
    {
        float x = W[W_VIEWS+3*v], y = W[W_VIEWS+3*v+1], z = W[W_VIEWS+3*v+2];
        float na = x*x + y*y + z*z;
        float best = INFINITY; int bi = 0x7fffffff;
        for (int v2 = lane; v2 < NV; v2 += 64) {
            float d = na + vn[v2] - 2.f*(x*vtx[v2] + y*vty[v2] + z*vtz[v2]);
            if (d < best) { best = d; bi = v2; }
        }
#pragma unroll
        for (int off = 32; off > 0; off >>= 1) {
            float ov = __shfl_down(best, off); int oi = __shfl_down(bi, off);
            if (ov < best || (ov == best && oi < bi)) { best = ov; bi = oi; }
        }
        if (lane == 0) { s_vi = bi; IB[PB_VIND + v] = bi; }
    }
    __syncthreads();
    int vi = s_vi;
    int a = lane;
    if (a < NA) {
        const float* G = W + W_GROT + 9*(vi*NA + a);
        float rt[9];
#pragma unroll
        for (int i=0;i<3;++i)
#pragma unroll
            for (int j=0;j<3;++j)
                rt[i*3+j] = P[i*4+0]*G[0*3+j] + P[i*4+1]*G[1*3+j] + P[i*4+2]*G[2*3+j];
#pragma unroll
        for (int q=0;q<9;++q) rtr[a][q]=rt[q];
        float t1[12], t2[12];
        kp12(rt, C_L, t1); kp12(rt, C_LS, t2);
#pragma unroll
        for (int k=0;k<12;++k) { tk[a][k]=t1[k]; tks[a][k]=t2[k]; }
    }
    __syncthreads();
    if (a < NA) {
        const float* pk = W + W_PKP + 12*(v*NA + a);
        float pkl[12];
#pragma unroll
        for (int k=0;k<12;++k) pkl[k]=pk[k];
        float m1=INFINITY, m2=INFINITY; int i1=0, i2=0;
        for (int ap=0; ap<NA; ++ap) {
            float d1=0.f, d2=0.f;
#pragma unroll
            for (int k=0;k<12;++k) {
                float e1 = pkl[k]-tk[ap][k];  d1 += e1*e1;
                float e2 = pkl[k]-tks[ap][k]; d2 += e2*e2;
            }
            if (d1 < m1) { m1=d1; i1=ap; }
            if (d2 < m2) { m2=d2; i2=ap; }
        }
        int ind = (m1 < m2) ? i1 : i2;
        int mi = v*NA + a;
        IB[PB_AIND + mi] = ind;
        float sel[9];
#pragma unroll
        for (int q=0;q<9;++q) { sel[q]=rtr[ind][q]; WB[PB_ROT + 9*mi + q] = sel[q]; }
        float tb[12], tbs[12];
        kp12(sel, C_L, tb); kp12(sel, C_LS, tbs);
        float s1=0.f, s2=0.f;
#pragma unroll
        for (int k=0;k<12;++k) {
            WB[PB_TB +k*NM+mi]=tb[k];  s1 += tb[k]*tb[k];   // transposed [12][NM]
            WB[PB_TBS+k*NM+mi]=tbs[k]; s2 += tbs[k]*tbs[k]; // transposed [12][NM]
        }
        WB[PB_TN1+mi]=s1; WB[PB_TN2+mi]=s2;
    }
}

// K3: fused nn + final, NSP=4 seeds per 256-thread block (amortizes TB/TBS L2 reads)
__global__ void k_nf(const float* __restrict__ pc,
                     const float* __restrict__ r6p, const float* __restrict__ dpp,
                     const float* __restrict__ labels, const float* __restrict__ offsets,
                     float* __restrict__ W, float* __restrict__ out, int B) {
    int b = blockIdx.y;
    int s0 = blockIdx.x*NSP;
    int tid = threadIdx.x;
    int wv = tid >> 6, lane = tid & 63;
    float* WB = W + W_BATCH + (size_t)b*SB;
    const int* IB = (const int*)W + W_BATCH + (size_t)b*SB;

    __shared__ float gx[NG], gy[NG], gz[NG], gn[NG];
    for (int i = tid; i < NG; i += 256) {
        float x = WB[PB_GPT+3*i], y = WB[PB_GPT+3*i+1], z = WB[PB_GPT+3*i+2];
        gx[i]=x; gy[i]=y; gz[i]=z; gn[i]=x*x+y*y+z*z;
    }
    __syncthreads();

    // --- nn: wave wv handles seed s0+wv (same structure as passing round-5 k_nn) ---
    __shared__ int s_nn[NSP];
    {
        int s = s0 + wv;
        float px = pc[((size_t)b*NS+s)*3+0], py = pc[((size_t)b*NS+s)*3+1], pz = pc[((size_t)b*NS+s)*3+2];
        float pn = px*px+py*py+pz*pz;
        float nbest = INFINITY; int nbi = 0x7fffffff;
        for (int g = lane; g < NG; g += 64) {
            float d = pn + gn[g] - 2.f*(px*gx[g]+py*gy[g]+pz*gz[g]);
            if (d < nbest) { nbest = d; nbi = g; }
        }
#pragma unroll
        for (int off = 32; off > 0; off >>= 1) {
            float ov = __shfl_down(nbest, off); int oi = __shfl_down(nbi, off);
            if (ov < nbest || (ov == nbest && oi < nbi)) { nbest = ov; nbi = oi; }
        }
        if (lane == 0) s_nn[wv] = nbi;
    }

    // --- pb for all NSP seeds (redundant per thread, cheap) ---
    float pb[NSP][12]; float Pn[NSP];
#pragma unroll
    for (int ss = 0; ss < NSP; ++ss) {
        const float* r6 = r6p + 6*((size_t)b*NS + s0 + ss);
        float a1x=r6[0],a1y=r6[1],a1z=r6[2],a2x=r6[3],a2y=r6[4],a2z=r6[5];
        float n1 = sqrtf(a1x*a1x+a1y*a1y+a1z*a1z);
        float b1x=a1x/n1, b1y=a1y/n1, b1z=a1z/n1;
        float dt = b1x*a2x+b1y*a2y+b1z*a2z;
        float p2x=a2x-dt*b1x, p2y=a2y-dt*b1y, p2z=a2z-dt*b1z;
        float n2 = sqrtf(p2x*p2x+p2y*p2y+p2z*p2z);
        float b2x=p2x/n2, b2y=p2y/n2, b2z=p2z/n2;
        float b3x=b1y*b2z-b1z*b2y, b3y=b1z*b2x-b1x*b2z, b3z=b1x*b2y-b1y*b2x;
        float Rp[9] = {b1x,b1y,b1z, b2x,b2y,b2z, b3x,b3y,b3z};
        kp12(Rp, C_L, pb[ss]);
        float pnorm = 0.f;
#pragma unroll
        for (int k=0;k<12;++k) pnorm += pb[ss][k]*pb[ss][k];
        Pn[ss] = pnorm;
    }

    // --- rot-scan: same per-thread j-assignment as before, NSP accumulators ---
    float m1[NSP], m2[NSP]; int i1[NSP], i2[NSP];
#pragma unroll
    for (int ss=0; ss<NSP; ++ss) { m1[ss]=INFINITY; m2[ss]=INFINITY; i1[ss]=0x7fffffff; i2[ss]=0x7fffffff; }
#pragma unroll
    for (int it = 0; it < 4; ++it) {
        int j0 = it*1024 + tid*4;
        if (j0 < NM) {
            float dot1[NSP][4], dot2[NSP][4];
#pragma unroll
            for (int ss=0; ss<NSP; ++ss)
#pragma unroll
                for (int q=0;q<4;++q) { dot1[ss][q]=0.f; dot2[ss][q]=0.f; }
#pragma unroll
            for (int k=0;k<12;++k) {
                float4 tb  = *reinterpret_cast<const float4*>(&WB[PB_TB  + k*NM + j0]);
                float4 tbs = *reinterpret_cast<const float4*>(&WB[PB_TBS + k*NM + j0]);
#pragma unroll
                for (int ss=0; ss<NSP; ++ss) {
                    float p = pb[ss][k];
                    dot1[ss][0] += p*tb.x;  dot1[ss][1] += p*tb.y;
                    dot1[ss][2] += p*tb.z;  dot1[ss][3] += p*tb.w;
                    dot2[ss][0] += p*tbs.x; dot2[ss][1] += p*tbs.y;
                    dot2[ss][2] += p*tbs.z; dot2[ss][3] += p*tbs.w;
                }
            }
            float4 tn1 = *reinterpret_cast<const float4*>(&WB[PB_TN1 + j0]);
            float4 tn2 = *reinterpret_cast<const float4*>(&WB[PB_TN2 + j0]);
            float n1v[4] = {tn1.x,tn1.y,tn1.z,tn1.w};
            float n2v[4] = {tn2.x,tn2.y,tn2.z,tn2.w};
#pragma unroll
            for (int q=0;q<4;++q) {
                int j = j0 + q;
#pragma unroll
                for (int ss=0; ss<NSP; ++ss) {
                    float d1 = Pn[ss] + n1v[q] - 2.f*dot1[ss][q];
                    float d2 = Pn[ss] + n2v[q] - 2.f*dot2[ss][q];
                    if (d1 < m1[ss]) { m1[ss]=d1; i1[ss]=j; }
                    if (d2 < m2[ss]) { m2[ss]=d2; i2[ss]=j; }
                }
            }
        }
    }
    // wave reduce per seed (val asc, idx tie -> smaller)
#pragma unroll
    for (int off = 32; off > 0; off >>= 1) {
#pragma unroll
        for (int ss=0; ss<NSP; ++ss) {
            float o1 = __shfl_down(m1[ss], off); int oi1 = __shfl_down(i1[ss], off);
            if (o1 < m1[ss] || (o1 == m1[ss] && oi1 < i1[ss])) { m1[ss] = o1; i1[ss] = oi1; }
            float o2 = __shfl_down(m2[ss], off); int oi2 = __shfl_down(i2[ss], off);
            if (o2 < m2[ss] || (o2 == m2[ss] && oi2 < i2[ss])) { m2[ss] = o2; i2[ss] = oi2; }
        }
    }
    __shared__ float sm1[NSP][4], sm2[NSP][4];
    __shared__ int   si1[NSP][4], si2[NSP][4];
    if (lane == 0) {
#pragma unroll
        for (int ss=0; ss<NSP; ++ss) {
            sm1[ss][wv]=m1[ss]; si1[ss][wv]=i1[ss];
            sm2[ss][wv]=m2[ss]; si2[ss][wv]=i2[ss];
        }
    }
    __syncthreads();
    if (tid >= NSP) return;
    int ss = tid;
    int s = s0 + ss;
    float M1 = sm1[ss][0], M2 = sm2[ss][0];
    int   I1 = si1[ss][0], I2 = si2[ss][0];
#pragma unroll
    for (int w = 1; w < 4; ++w) {
        if (sm1[ss][w] < M1 || (sm1[ss][w] == M1 && si1[ss][w] < I1)) { M1 = sm1[ss][w]; I1 = si1[ss][w]; }
        if (sm2[ss][w] < M2 || (sm2[ss][w] == M2 && si2[ss][w] < I2)) { M2 = sm2[ss][w]; I2 = si2[ss][w]; }
    }
    int rot_ind = (M1 < M2) ? I1 : I2;
    int nn_s = s_nn[ss];

    float dp = dpp[(size_t)b*NS+s];
    float bd = INFINITY; int di = 0;
#pragma unroll
    for (int d = 0; d < ND; ++d) {
        float dv = (float)(0.01 + 0.01*(double)d);
        float ad = fabsf(dp - dv);
        if (ad < bd) { bd = ad; di = d; }
    }

    int v_out = rot_ind / NA;
    int vi = IB[PB_VIND + v_out];
    int ai = IB[PB_AIND + rot_ind];
    size_t lidx = ((((size_t)b*NG+nn_s)*NV + vi)*NA + ai)*ND + di;
    float gs = labels[lidx];
    float gw = offsets[lidx];

    int bs = b*NS + s;
    int oRot = B*NS*3;
    int oSc  = oRot + B*NS*6;
    int oWd  = oSc  + B*NS;
    int oDp  = oWd  + B*NS;
    int oWid = oDp  + B*NS;
    int oSid = oWid + B*NS;

    out[3*bs+0]=gx[nn_s]; out[3*bs+1]=gy[nn_s]; out[3*bs+2]=gz[nn_s];
    const float* Rsel = WB + PB_ROT + 9*rot_ind;
#pragma unroll
    for (int q=0;q<6;++q) out[oRot + 6*bs + q] = Rsel[q];

    bool mask = (gs > 0.f) && (gw <= 0.1f);
    float sc = mask ? (1.1f - gs) : 0.f;
    out[oSc + bs] = sc;
    out[oWd + bs] = gw;
    out[oDp + bs] = (float)(0.01 + 0.01*(double)di);

    int wid = 0;
    wid += (0.02f < gw); wid += (0.04f < gw); wid += (0.06f < gw); wid += (0.08f < gw);
    const float sbins[9] = {0.1f,0.2f,0.3f,0.4f,0.5f,0.6f,0.7f,0.8f,0.9f};
    int sid = 0;
#pragma unroll
    for (int i=0;i<9;++i) sid += (sbins[i] < sc) ? 1 : 0;
    out[oWid + bs] = (float)wid;
    out[oSid + bs] = (float)sid;
}

extern "C" void kernel_launch(void* const* d_in, const int* in_sizes, int n_in,
                              void* d_out, int out_size, void* d_ws, size_t ws_size,
                              hipStream_t stream) {
    const float* pc      = (const float*)d_in[0];
    const float* pose    = (const float*)d_in[1];
    const float* gp      = (const float*)d_in[2];
    const float* labels  = (const float*)d_in[3];
    const float* offsets = (const float*)d_in[4];
    const float* r6      = (const float*)d_in[5];
    const float* dpp     = (const float*)d_in[6];
    float* W   = (float*)d_ws;
    float* out = (float*)d_out;
    int B = in_sizes[1] / 12;

    hipLaunchKernelGGL(k_setup, dim3(15 + B*(NG/256)), dim3(256), 0, stream, pose, gp, W);
    hipLaunchKernelGGL(k_va,    dim3(NV, B), dim3(64), 0, stream, pose, W);
    hipLaunchKernelGGL(k_nf,    dim3(NS/NSP, B), dim3(256), 0, stream,
                       pc, r6, dpp, labels, offsets, W, out, B);
}

// Round 15
// 262.683 us; speedup vs baseline: 1.1451x; 1.1451x over previous
//
#include <hip/hip_runtime.h>

#define NV 300
#define NA 12
#define ND 4
#define NM (NV*NA)
#define NS 1024
#define NG 1024
#define NSP 4

// workspace float offsets
#define W_VIEWS 0          // 900
#define W_GROT  900        // 32400
#define W_PKP   33300      // 43200
#define W_BATCH 76500
#define SB      134032     // per-batch stride (floats)

#define PB_GPT  0          // 3072
#define PB_ROT  3072       // 32400
#define PB_TB   35472      // 43200 (transposed: [12][NM])
#define PB_TBS  78672      // 43200 (transposed: [12][NM])
#define PB_TN1  121872     // 3600
#define PB_TN2  125472     // 3600
#define PB_VIND 129072     // 300 ints
#define PB_AIND 129372     // 3600 ints

__constant__ float C_L[4][3]  = {{0.02f,0.f,0.f},{0.02f,0.01f,0.f},{0.02f,-0.01f,0.f},{0.f,0.f,0.f}};
__constant__ float C_LS[4][3] = {{0.02f,0.f,0.f},{0.02f,-0.01f,0.f},{0.02f,0.01f,0.f},{0.f,0.f,0.f}};

__device__ __forceinline__ void kp12(const float R[9], const float (*L)[3], float out[12]) {
#pragma unroll
    for (int k = 0; k < 4; ++k)
#pragma unroll
        for (int i = 0; i < 3; ++i)
            out[k*3+i] = R[i*3+0]*L[k][0] + R[i*3+1]*L[k][1] + R[i*3+2]*L[k][2];
}

// fp64 Fibonacci-sphere view i (identical formula to numpy reference)
__device__ __forceinline__ void view_d(int i, float* vx, float* vy, float* vz) {
    const double PI = 3.14159265358979323846;
    double phi = (sqrt(5.0) - 1.0) * 0.5;
    double z = (2.0*i + 1.0)/(double)NV - 1.0;
    double r2 = 1.0 - z*z; r2 = r2 > 0.0 ? r2 : 0.0;
    double r = sqrt(r2);
    double ang = 2.0*PI*(double)i*phi;
    *vx = (float)(r*cos(ang));
    *vy = (float)(r*sin(ang));
    *vz = (float)z;
}

// K1: blocks 0..14 -> views + GRASP_ROT + pkp; blocks 15.. -> gp_trans
__global__ void k_setup(const float* __restrict__ pose, const float* __restrict__ gp,
                        float* W) {
    int bid = blockIdx.x;
    if (bid < 15) {
        int m = bid*256 + threadIdx.x;
        if (m >= NM) return;
        if (m < NV) {
            float x,y,z; view_d(m, &x,&y,&z);
            W[W_VIEWS + 3*m+0] = x; W[W_VIEWS + 3*m+1] = y; W[W_VIEWS + 3*m+2] = z;
        }
        int vi = m / NA, ai = m % NA;
        float vx,vy,vz; view_d(vi, &vx,&vy,&vz);
        float tx = -vx, ty = -vy, tz = -vz;
        float nrm = sqrtf(tx*tx + ty*ty + tz*tz);
        float ax0 = tx/nrm, ax1 = ty/nrm, ax2 = tz/nrm;
        float ay0 = -ax1, ay1 = ax0, ay2 = 0.f;
        float n2 = sqrtf(ay0*ay0 + ay1*ay1 + ay2*ay2);
        if (n2 > 1e-8f) { float d = fmaxf(n2, 1e-12f); ay0 /= d; ay1 /= d; ay2 /= d; }
        else { ay0 = 0.f; ay1 = 1.f; ay2 = 0.f; }
        float az0 = ax1*ay2 - ax2*ay1;
        float az1 = ax2*ay0 - ax0*ay2;
        float az2 = ax0*ay1 - ax1*ay0;
        float angle = (float)(3.14159265358979323846/12.0*(double)ai);
        float c = cosf(angle), s = sinf(angle);
        float G[9];
        G[0]=ax0; G[1]=ay0*c+az0*s; G[2]=-ay0*s+az0*c;
        G[3]=ax1; G[4]=ay1*c+az1*s; G[5]=-ay1*s+az1*c;
        G[6]=ax2; G[7]=ay2*c+az2*s; G[8]=-ay2*s+az2*c;
#pragma unroll
        for (int q=0;q<9;++q) W[W_GROT + 9*m + q] = G[q];
        float pk[12]; kp12(G, C_L, pk);
#pragma unroll
        for (int q=0;q<12;++q) W[W_PKP + 12*m + q] = pk[q];
    } else {
        int idx = (bid-15)*256 + threadIdx.x;   // over B*NG
        int b = idx >> 10, g = idx & (NG-1);
        const float* P = pose + 12*b;
        float x = gp[(size_t)idx*3+0], y = gp[(size_t)idx*3+1], z = gp[(size_t)idx*3+2];
        float* o = W + W_BATCH + (size_t)b*SB + PB_GPT + 3*g;
        o[0] = P[0]*x + P[1]*y + P[2]*z  + P[3];
        o[1] = P[4]*x + P[5]*y + P[6]*z  + P[7];
        o[2] = P[8]*x + P[9]*y + P[10]*z + P[11];
    }
}

// K2: fused vind + align. one 64-thread block per (v, b)
__global__ void k_va(const float* __restrict__ pose, float* W) {
    int v = blockIdx.x, b = blockIdx.y;
    float* WB = W + W_BATCH + (size_t)b*SB;
    int* IB = (int*)W + W_BATCH + (size_t)b*SB;
    const float* P = pose + 12*b;
    int lane = threadIdx.x;  // 0..63, one wave

    __shared__ float vtx[NV], vty[NV], vtz[NV], vn[NV];
    __shared__ float rtr[NA][9];
    __shared__ float tk[NA][12], tks[NA][12];
    __shared__ int s_vi;

    for (int i = lane; i < NV; i += 64) {
        float x = W[W_VIEWS+3*i], y = W[W_VIEWS+3*i+1], z = W[W_VIEWS+3*i+2];
        float a = P[0]*x+P[1]*y+P[2]*z;
        float c = P[4]*x+P[5]*y+P[6]*z;
        float d = P[8]*x+P[9]*y+P[10]*z;
        vtx[i]=a; vty[i]=c; vtz[i]=d;
        vn[i] = a*a + c*c + d*d;
    }
    __syncthreads();
    {
        float x = W[W_VIEWS+3*v], y = W[W_VIEWS+3*v+1], z = W[W_VIEWS+3*v+2];
        float na = x*x + y*y + z*z;
        float best = INFINITY; int bi = 0x7fffffff;
        for (int v2 = lane; v2 < NV; v2 += 64) {
            float d = na + vn[v2] - 2.f*(x*vtx[v2] + y*vty[v2] + z*vtz[v2]);
            if (d < best) { best = d; bi = v2; }
        }
#pragma unroll
        for (int off = 32; off > 0; off >>= 1) {
            float ov = __shfl_down(best, off); int oi = __shfl_down(bi, off);
            if (ov < best || (ov == best && oi < bi)) { best = ov; bi = oi; }
        }
        if (lane == 0) { s_vi = bi; IB[PB_VIND + v] = bi; }
    }
    __syncthreads();
    int vi = s_vi;
    int a = lane;
    if (a < NA) {
        const float* G = W + W_GROT + 9*(vi*NA + a);
        float rt[9];
#pragma unroll
        for (int i=0;i<3;++i)
#pragma unroll
            for (int j=0;j<3;++j)
                rt[i*3+j] = P[i*4+0]*G[0*3+j] + P[i*4+1]*G[1*3+j] + P[i*4+2]*G[2*3+j];
#pragma unroll
        for (int q=0;q<9;++q) rtr[a][q]=rt[q];
        float t1[12], t2[12];
        kp12(rt, C_L, t1); kp12(rt, C_LS, t2);
#pragma unroll
        for (int k=0;k<12;++k) { tk[a][k]=t1[k]; tks[a][k]=t2[k]; }
    }
    __syncthreads();
    if (a < NA) {
        const float* pk = W + W_PKP + 12*(v*NA + a);
        float pkl[12];
#pragma unroll
        for (int k=0;k<12;++k) pkl[k]=pk[k];
        float m1=INFINITY, m2=INFINITY; int i1=0, i2=0;
        for (int ap=0; ap<NA; ++ap) {
            float d1=0.f, d2=0.f;
#pragma unroll
            for (int k=0;k<12;++k) {
                float e1 = pkl[k]-tk[ap][k];  d1 += e1*e1;
                float e2 = pkl[k]-tks[ap][k]; d2 += e2*e2;
            }
            if (d1 < m1) { m1=d1; i1=ap; }
            if (d2 < m2) { m2=d2; i2=ap; }
        }
        int ind = (m1 < m2) ? i1 : i2;
        int mi = v*NA + a;
        IB[PB_AIND + mi] = ind;
        float sel[9];
#pragma unroll
        for (int q=0;q<9;++q) { sel[q]=rtr[ind][q]; WB[PB_ROT + 9*mi + q] = sel[q]; }
        float tb[12], tbs[12];
        kp12(sel, C_L, tb); kp12(sel, C_LS, tbs);
        float s1=0.f, s2=0.f;
#pragma unroll
        for (int k=0;k<12;++k) {
            WB[PB_TB +k*NM+mi]=tb[k];  s1 += tb[k]*tb[k];   // transposed [12][NM]
            WB[PB_TBS+k*NM+mi]=tbs[k]; s2 += tbs[k]*tbs[k]; // transposed [12][NM]
        }
        WB[PB_TN1+mi]=s1; WB[PB_TN2+mi]=s2;
    }
}

// K3: fused nn + final, NSP=4 seeds per block; pb/Pn staged in LDS to avoid
// the register-spill regression seen with per-thread pb arrays (r14: 100MB
// scratch writes/dispatch at VGPR=64).
__global__ void k_nf(const float* __restrict__ pc,
                     const float* __restrict__ r6p, const float* __restrict__ dpp,
                     const float* __restrict__ labels, const float* __restrict__ offsets,
                     float* __restrict__ W, float* __restrict__ out, int B) {
    int b = blockIdx.y;
    int s0 = blockIdx.x*NSP;
    int tid = threadIdx.x;
    int wv = tid >> 6, lane = tid & 63;
    float* WB = W + W_BATCH + (size_t)b*SB;
    const int* IB = (const int*)W + W_BATCH + (size_t)b*SB;

    __shared__ float gx[NG], gy[NG], gz[NG], gn[NG];
    for (int i = tid; i < NG; i += 256) {
        float x = WB[PB_GPT+3*i], y = WB[PB_GPT+3*i+1], z = WB[PB_GPT+3*i+2];
        gx[i]=x; gy[i]=y; gz[i]=z; gn[i]=x*x+y*y+z*z;
    }
    __syncthreads();

    // --- nn: wave wv handles seed s0+wv ---
    __shared__ int s_nn[NSP];
    {
        int s = s0 + wv;
        float px = pc[((size_t)b*NS+s)*3+0], py = pc[((size_t)b*NS+s)*3+1], pz = pc[((size_t)b*NS+s)*3+2];
        float pn = px*px+py*py+pz*pz;
        float nbest = INFINITY; int nbi = 0x7fffffff;
        for (int g = lane; g < NG; g += 64) {
            float d = pn + gn[g] - 2.f*(px*gx[g]+py*gy[g]+pz*gz[g]);
            if (d < nbest) { nbest = d; nbi = g; }
        }
#pragma unroll
        for (int off = 32; off > 0; off >>= 1) {
            float ov = __shfl_down(nbest, off); int oi = __shfl_down(nbi, off);
            if (ov < nbest || (ov == nbest && oi < nbi)) { nbest = ov; nbi = oi; }
        }
        if (lane == 0) s_nn[wv] = nbi;
    }

    // --- pb/Pn in LDS: thread ss computes seed s0+ss (bit-identical float ops) ---
    __shared__ float sh_pb[NSP][12];
    __shared__ float sh_Pn[NSP];
    if (tid < NSP) {
        const float* r6 = r6p + 6*((size_t)b*NS + s0 + tid);
        float a1x=r6[0],a1y=r6[1],a1z=r6[2],a2x=r6[3],a2y=r6[4],a2z=r6[5];
        float n1 = sqrtf(a1x*a1x+a1y*a1y+a1z*a1z);
        float b1x=a1x/n1, b1y=a1y/n1, b1z=a1z/n1;
        float dt = b1x*a2x+b1y*a2y+b1z*a2z;
        float p2x=a2x-dt*b1x, p2y=a2y-dt*b1y, p2z=a2z-dt*b1z;
        float n2 = sqrtf(p2x*p2x+p2y*p2y+p2z*p2z);
        float b2x=p2x/n2, b2y=p2y/n2, b2z=p2z/n2;
        float b3x=b1y*b2z-b1z*b2y, b3y=b1z*b2x-b1x*b2z, b3z=b1x*b2y-b1y*b2x;
        float Rp[9] = {b1x,b1y,b1z, b2x,b2y,b2z, b3x,b3y,b3z};
        float pbv[12]; kp12(Rp, C_L, pbv);
        float pnorm = 0.f;
#pragma unroll
        for (int k=0;k<12;++k) { sh_pb[tid][k]=pbv[k]; pnorm += pbv[k]*pbv[k]; }
        sh_Pn[tid] = pnorm;
    }
    __syncthreads();

    // --- rot-scan: same per-thread j-assignment, NSP accumulators (static idx) ---
    float m1[NSP], m2[NSP]; int i1[NSP], i2[NSP];
#pragma unroll
    for (int ss=0; ss<NSP; ++ss) { m1[ss]=INFINITY; m2[ss]=INFINITY; i1[ss]=0x7fffffff; i2[ss]=0x7fffffff; }
#pragma unroll
    for (int it = 0; it < 4; ++it) {
        int j0 = it*1024 + tid*4;
        if (j0 < NM) {
            float dot1[NSP][4], dot2[NSP][4];
#pragma unroll
            for (int ss=0; ss<NSP; ++ss)
#pragma unroll
                for (int q=0;q<4;++q) { dot1[ss][q]=0.f; dot2[ss][q]=0.f; }
#pragma unroll
            for (int k=0;k<12;++k) {
                float4 tb  = *reinterpret_cast<const float4*>(&WB[PB_TB  + k*NM + j0]);
                float4 tbs = *reinterpret_cast<const float4*>(&WB[PB_TBS + k*NM + j0]);
#pragma unroll
                for (int ss=0; ss<NSP; ++ss) {
                    float p = sh_pb[ss][k];   // LDS broadcast, conflict-free
                    dot1[ss][0] += p*tb.x;  dot1[ss][1] += p*tb.y;
                    dot1[ss][2] += p*tb.z;  dot1[ss][3] += p*tb.w;
                    dot2[ss][0] += p*tbs.x; dot2[ss][1] += p*tbs.y;
                    dot2[ss][2] += p*tbs.z; dot2[ss][3] += p*tbs.w;
                }
            }
            float4 tn1 = *reinterpret_cast<const float4*>(&WB[PB_TN1 + j0]);
            float4 tn2 = *reinterpret_cast<const float4*>(&WB[PB_TN2 + j0]);
            float n1v[4] = {tn1.x,tn1.y,tn1.z,tn1.w};
            float n2v[4] = {tn2.x,tn2.y,tn2.z,tn2.w};
#pragma unroll
            for (int q=0;q<4;++q) {
                int j = j0 + q;
#pragma unroll
                for (int ss=0; ss<NSP; ++ss) {
                    float d1 = sh_Pn[ss] + n1v[q] - 2.f*dot1[ss][q];
                    float d2 = sh_Pn[ss] + n2v[q] - 2.f*dot2[ss][q];
                    if (d1 < m1[ss]) { m1[ss]=d1; i1[ss]=j; }
                    if (d2 < m2[ss]) { m2[ss]=d2; i2[ss]=j; }
                }
            }
        }
    }
    // wave reduce per seed (val asc, idx tie -> smaller)
#pragma unroll
    for (int off = 32; off > 0; off >>= 1) {
#pragma unroll
        for (int ss=0; ss<NSP; ++ss) {
            float o1 = __shfl_down(m1[ss], off); int oi1 = __shfl_down(i1[ss], off);
            if (o1 < m1[ss] || (o1 == m1[ss] && oi1 < i1[ss])) { m1[ss] = o1; i1[ss] = oi1; }
            float o2 = __shfl_down(m2[ss], off); int oi2 = __shfl_down(i2[ss], off);
            if (o2 < m2[ss] || (o2 == m2[ss] && oi2 < i2[ss])) { m2[ss] = o2; i2[ss] = oi2; }
        }
    }
    __shared__ float sm1[NSP][4], sm2[NSP][4];
    __shared__ int   si1[NSP][4], si2[NSP][4];
    if (lane == 0) {
#pragma unroll
        for (int ss=0; ss<NSP; ++ss) {
            sm1[ss][wv]=m1[ss]; si1[ss][wv]=i1[ss];
            sm2[ss][wv]=m2[ss]; si2[ss][wv]=i2[ss];
        }
    }
    __syncthreads();
    if (tid >= NSP) return;
    int ss = tid;
    int s = s0 + ss;
    float M1 = sm1[ss][0], M2 = sm2[ss][0];
    int   I1 = si1[ss][0], I2 = si2[ss][0];
#pragma unroll
    for (int w = 1; w < 4; ++w) {
        if (sm1[ss][w] < M1 || (sm1[ss][w] == M1 && si1[ss][w] < I1)) { M1 = sm1[ss][w]; I1 = si1[ss][w]; }
        if (sm2[ss][w] < M2 || (sm2[ss][w] == M2 && si2[ss][w] < I2)) { M2 = sm2[ss][w]; I2 = si2[ss][w]; }
    }
    int rot_ind = (M1 < M2) ? I1 : I2;
    int nn_s = s_nn[ss];

    float dp = dpp[(size_t)b*NS+s];
    float bd = INFINITY; int di = 0;
#pragma unroll
    for (int d = 0; d < ND; ++d) {
        float dv = (float)(0.01 + 0.01*(double)d);
        float ad = fabsf(dp - dv);
        if (ad < bd) { bd = ad; di = d; }
    }

    int v_out = rot_ind / NA;
    int vi = IB[PB_VIND + v_out];
    int ai = IB[PB_AIND + rot_ind];
    size_t lidx = ((((size_t)b*NG+nn_s)*NV + vi)*NA + ai)*ND + di;
    float gs = labels[lidx];
    float gw = offsets[lidx];

    int bs = b*NS + s;
    int oRot = B*NS*3;
    int oSc  = oRot + B*NS*6;
    int oWd  = oSc  + B*NS;
    int oDp  = oWd  + B*NS;
    int oWid = oDp  + B*NS;
    int oSid = oWid + B*NS;

    out[3*bs+0]=gx[nn_s]; out[3*bs+1]=gy[nn_s]; out[3*bs+2]=gz[nn_s];
    const float* Rsel = WB + PB_ROT + 9*rot_ind;
#pragma unroll
    for (int q=0;q<6;++q) out[oRot + 6*bs + q] = Rsel[q];

    bool mask = (gs > 0.f) && (gw <= 0.1f);
    float sc = mask ? (1.1f - gs) : 0.f;
    out[oSc + bs] = sc;
    out[oWd + bs] = gw;
    out[oDp + bs] = (float)(0.01 + 0.01*(double)di);

    int wid = 0;
    wid += (0.02f < gw); wid += (0.04f < gw); wid += (0.06f < gw); wid += (0.08f < gw);
    const float sbins[9] = {0.1f,0.2f,0.3f,0.4f,0.5f,0.6f,0.7f,0.8f,0.9f};
    int sid = 0;
#pragma unroll
    for (int i=0;i<9;++i) sid += (sbins[i] < sc) ? 1 : 0;
    out[oWid + bs] = (float)wid;
    out[oSid + bs] = (float)sid;
}

extern "C" void kernel_launch(void* const* d_in, const int* in_sizes, int n_in,
                              void* d_out, int out_size, void* d_ws, size_t ws_size,
                              hipStream_t stream) {
    const float* pc      = (const float*)d_in[0];
    const float* pose    = (const float*)d_in[1];
    const float* gp      = (const float*)d_in[2];
    const float* labels  = (const float*)d_in[3];
    const float* offsets = (const float*)d_in[4];
    const float* r6      = (const float*)d_in[5];
    const float* dpp     = (const float*)d_in[6];
    float* W   = (float*)d_ws;
    float* out = (float*)d_out;
    int B = in_sizes[1] / 12;

    hipLaunchKernelGGL(k_setup, dim3(15 + B*(NG/256)), dim3(256), 0, stream, pose, gp, W);
    hipLaunchKernelGGL(k_va,    dim3(NV, B), dim3(64), 0, stream, pose, W);
    hipLaunchKernelGGL(k_nf,    dim3(NS/NSP, B), dim3(256), 0, stream,
                       pc, r6, dpp, labels, offsets, W, out, B);
}